// Round 7
// baseline (86.778 us; speedup 1.0000x reference)
//
#include <hip/hip_runtime.h>

// Problem constants (from reference)
#define V 49688
#define D 128
#define B 16
#define N 100
#define VD (V * D)        // 6,360,064 floats per batch
#define VD4 (VD / 4)      // 1,590,016 float4 per batch
#define BN (B * N)        // 1600 scatter rows
#define CHUNK 1024        // f4 per block = 32 rows
#define NBLK ((VD4 + CHUNK - 1) / CHUNK)   // 1553 (last block: 768 f4 = 24 rows)
#define MAXH 64           // hit-list cap (E[hits/block] ~= 1.03; 64 is untouchable)

typedef float f32x4 __attribute__((ext_vector_type(4)));

// Fused kernel (R7): NT-broadcast copy at ILP=4 (R5's 79.9us structure,
// byte-identical store schedule) + in-kernel scatter. Each block owns rows
// [bid*32, bid*32+32); it scans nodes[] for rows it owns (expected ~1 hit),
// and during the 16-batch broadcast substitutes the gated blend
// (1-a)*W[v] + a*x[i] for hit rows of the hit batch. Removes the second
// kernel, its launch/serialization, and the 0.8MB double-write.
__global__ __launch_bounds__(256) void GlobalGatedUpdate_fused_kernel(
    const int* __restrict__ nodes, const float* __restrict__ x,
    const f32x4* __restrict__ W4, const float* __restrict__ alpha,
    f32x4* __restrict__ out4) {
  __shared__ int s_nhits;
  __shared__ int s_hits[MAXH];   // packed (b<<12)|(i<<5)|r
  const int t = threadIdx.x;
  const int c = blockIdx.x * CHUNK + t;       // base f4 index
  const int row0 = blockIdx.x * 32;           // first W-row owned by block
  if (t == 0) s_nhits = 0;
  __syncthreads();

  // Issue the 4 W loads first (HBM latency overlaps the nodes scan).
  f32x4 v0, v1, v2, v3;
  const bool g0 = c + 0 * 256 < VD4;
  const bool g1 = c + 1 * 256 < VD4;
  const bool g2 = c + 2 * 256 < VD4;
  const bool g3 = c + 3 * 256 < VD4;
  if (g0) v0 = W4[c + 0 * 256];
  if (g1) v1 = W4[c + 1 * 256];
  if (g2) v2 = W4[c + 2 * 256];
  if (g3) v3 = W4[c + 3 * 256];

  // Scan nodes for rows in [row0, row0+32). 1600 ints, L2-hot.
  for (int j = t; j < BN; j += 256) {
    int vrow = nodes[j];
    int r = vrow - row0;
    if (r >= 0 && r < 32) {
      int b = j / N;
      int i = j - b * N;
      int p = atomicAdd(&s_nhits, 1);
      if (p < MAXH) s_hits[p] = (b << 12) | (i << 5) | r;
    }
  }
  __syncthreads();
  int nh = s_nhits > MAXH ? MAXH : s_nhits;

  const int tr  = t >> 5;   // which row-octave this thread's k-th f4 lives in
  const int col = t & 31;   // f4 column within a row

  #pragma unroll
  for (int b = 0; b < B; ++b) {
    f32x4 s0 = v0, s1 = v1, s2 = v2, s3 = v3;
    for (int h = 0; h < nh; ++h) {        // uniform; nh ~1, usually 0 matches
      int pk = s_hits[h];
      if ((pk >> 12) != b) continue;
      int r = pk & 31;                    // local row 0..31 (f4 k = r>>3)
      if (tr == (r & 7)) {                // 32 threads own this row
        int i = (pk >> 5) & 127;          // position in node list -> x row
        float a = alpha[row0 + r];
        f32x4 xv = ((const f32x4*)x)[i * 32 + col];
        #pragma unroll
        for (int k = 0; k < 4; ++k) {
          if ((r >> 3) == k) {            // static index into s0..s3
            f32x4 wv = k == 0 ? v0 : k == 1 ? v1 : k == 2 ? v2 : v3;
            f32x4 nv = (1.0f - a) * wv + a * xv;
            if (k == 0) s0 = nv; else if (k == 1) s1 = nv;
            else if (k == 2) s2 = nv; else s3 = nv;
          }
        }
      }
    }
    f32x4* dst = out4 + (size_t)b * VD4 + c;
    if (g0) __builtin_nontemporal_store(s0, dst + 0 * 256);
    if (g1) __builtin_nontemporal_store(s1, dst + 1 * 256);
    if (g2) __builtin_nontemporal_store(s2, dst + 2 * 256);
    if (g3) __builtin_nontemporal_store(s3, dst + 3 * 256);
  }
}

extern "C" void kernel_launch(void* const* d_in, const int* in_sizes, int n_in,
                              void* d_out, int out_size, void* d_ws, size_t ws_size,
                              hipStream_t stream) {
  const int*   nodes = (const int*)d_in[0];   // (B, N) int32
  const float* x     = (const float*)d_in[1]; // (B*N, D) f32
  const float* W     = (const float*)d_in[2]; // (V, D) f32
  const float* alpha = (const float*)d_in[3]; // (V, 1) f32
  float* out = (float*)d_out;                 // (B, V, D) f32

  GlobalGatedUpdate_fused_kernel<<<NBLK, 256, 0, stream>>>(
      nodes, x, (const f32x4*)W, alpha, (f32x4*)out);
}

// Round 8
// 84.705 us; speedup vs baseline: 1.0245x; 1.0245x over previous
//
#include <hip/hip_runtime.h>

// Problem constants (from reference)
#define V 49688
#define D 128
#define B 16
#define N 100
#define VD (V * D)        // 6,360,064 floats per batch
#define VD4 (VD / 4)      // 1,590,016 float4 per batch
#define CHUNK 1024        // f4 per block-x
#define NBLK ((VD4 + CHUNK - 1) / CHUNK)   // 1553

typedef float f32x4 __attribute__((ext_vector_type(4)));

// Kernel 1 (R8): NT broadcast, ILP=4, batch-split grid.y=2.
// Ladder: ILP1=88, ILP4=79.9 (best), ILP8=85.9, fused=86.8. Hypothesis for
// the ILP8 regression + residual 5.7-vs-7.0 TB/s gap: outstanding-VMEM
// tracker (~63 entries) — R5's 68 VMEM ops/wave stall issue at burst tail.
// y-split keeps read-MLP=4 and 4KB bursts but cuts stores/wave to 32
// (36 ops total, under cap) and doubles resident waves. Cost: W read twice
// (2nd pass L3-hot, +25MB).
__global__ __launch_bounds__(256) void GlobalGatedUpdate_copy_kernel(
    const f32x4* __restrict__ W4, f32x4* __restrict__ out4) {
  int c = blockIdx.x * CHUNK + threadIdx.x;  // base f4 index of this thread
  f32x4 v0, v1, v2, v3;
  const bool g0 = c + 0 * 256 < VD4;
  const bool g1 = c + 1 * 256 < VD4;
  const bool g2 = c + 2 * 256 < VD4;
  const bool g3 = c + 3 * 256 < VD4;
  if (g0) v0 = W4[c + 0 * 256];
  if (g1) v1 = W4[c + 1 * 256];
  if (g2) v2 = W4[c + 2 * 256];
  if (g3) v3 = W4[c + 3 * 256];
  const int b0 = blockIdx.y * 8;             // batches [b0, b0+8)
  #pragma unroll
  for (int bb = 0; bb < 8; ++bb) {
    f32x4* dst = out4 + (size_t)(b0 + bb) * VD4 + c;
    if (g0) __builtin_nontemporal_store(v0, dst + 0 * 256);
    if (g1) __builtin_nontemporal_store(v1, dst + 1 * 256);
    if (g2) __builtin_nontemporal_store(v2, dst + 2 * 256);
    if (g3) __builtin_nontemporal_store(v3, dst + 3 * 256);
  }
}

// Kernel 2: for each (b, i): v = nodes[b*N+i];
//   out[b][v][:] = (1 - alpha[v]) * W[v][:] + alpha[v] * x[i][:]
__global__ __launch_bounds__(256) void GlobalGatedUpdate_scatter_kernel(
    const int* __restrict__ nodes, const float* __restrict__ x,
    const float* __restrict__ W, const float* __restrict__ alpha,
    float* __restrict__ out) {
  int t = blockIdx.x * 256 + threadIdx.x;            // 0 .. B*N*32 - 1
  int d4  = t & 31;                                  // float4 index within row
  int row = t >> 5;                                  // 0 .. 1599 (= b*N + i)
  int b = row / N;
  int i = row - b * N;                               // position in node list -> x row
  int v = nodes[row];
  float a = alpha[v];                                // alpha is (V,1)
  f32x4 wv = ((const f32x4*)W)[v * 32 + d4];
  f32x4 xv = ((const f32x4*)x)[i * 32 + d4];
  f32x4 res = (1.0f - a) * wv + a * xv;
  ((f32x4*)out)[(size_t)b * (size_t)VD4 + (size_t)(v * 32 + d4)] = res;
}

extern "C" void kernel_launch(void* const* d_in, const int* in_sizes, int n_in,
                              void* d_out, int out_size, void* d_ws, size_t ws_size,
                              hipStream_t stream) {
  const int*   nodes = (const int*)d_in[0];   // (B, N) int32
  const float* x     = (const float*)d_in[1]; // (B*N, D) f32
  const float* W     = (const float*)d_in[2]; // (V, D) f32
  const float* alpha = (const float*)d_in[3]; // (V, 1) f32
  float* out = (float*)d_out;                 // (B, V, D) f32

  dim3 grid_copy(NBLK, 2);                    // 1553 x 2 (batch halves)
  GlobalGatedUpdate_copy_kernel<<<grid_copy, 256, 0, stream>>>(
      (const f32x4*)W, (f32x4*)out);

  GlobalGatedUpdate_scatter_kernel<<<(B * N * 32) / 256, 256, 0, stream>>>(
      nodes, x, W, alpha, out);
}

// Round 9
// 81.064 us; speedup vs baseline: 1.0705x; 1.0449x over previous
//
#include <hip/hip_runtime.h>

// Problem constants (from reference)
#define V 49688
#define D 128
#define B 16
#define N 100
#define VD (V * D)        // 6,360,064 floats per batch
#define VD4 (VD / 4)      // 1,590,016 float4 per batch (= 256 * 6211; 6211 prime)

typedef float f32x4 __attribute__((ext_vector_type(4)));

// Kernel 1 (R5 restored — session best, 79.9us): NT broadcast with ILP=4.
// Each thread loads 4 independent float4 of W, then stores them to all 16
// batch regions (4 consecutive 1KB wave-bursts per region). NT stores keep
// the 407MB write stream out of L2; W read once (25MB).
// Tested and rejected: ILP1 (88.0), ILP8 (85.9), plain stores (94.7),
// contiguous per-batch dispatch (122.9), fused scatter (86.8),
// batch-split y=2 (84.7).
__global__ __launch_bounds__(256) void GlobalGatedUpdate_copy_kernel(
    const f32x4* __restrict__ W4, f32x4* __restrict__ out4) {
  int c = blockIdx.x * 1024 + threadIdx.x;   // base f4 index of this thread
  f32x4 v0, v1, v2, v3;
  bool g0 = (c + 0 * 256) < VD4;
  bool g1 = (c + 1 * 256) < VD4;
  bool g2 = (c + 2 * 256) < VD4;
  bool g3 = (c + 3 * 256) < VD4;
  if (g0) v0 = W4[c + 0 * 256];
  if (g1) v1 = W4[c + 1 * 256];
  if (g2) v2 = W4[c + 2 * 256];
  if (g3) v3 = W4[c + 3 * 256];
  #pragma unroll
  for (int b = 0; b < B; ++b) {
    f32x4* dst = out4 + (size_t)b * VD4 + c;
    if (g0) __builtin_nontemporal_store(v0, dst + 0 * 256);
    if (g1) __builtin_nontemporal_store(v1, dst + 1 * 256);
    if (g2) __builtin_nontemporal_store(v2, dst + 2 * 256);
    if (g3) __builtin_nontemporal_store(v3, dst + 3 * 256);
  }
}

// Kernel 2: for each (b, i): v = nodes[b*N+i];
//   out[b][v][:] = (1 - alpha[v]) * W[v][:] + alpha[v] * x[i][:]
__global__ __launch_bounds__(256) void GlobalGatedUpdate_scatter_kernel(
    const int* __restrict__ nodes, const float* __restrict__ x,
    const float* __restrict__ W, const float* __restrict__ alpha,
    float* __restrict__ out) {
  int t = blockIdx.x * 256 + threadIdx.x;            // 0 .. B*N*32 - 1
  int d4  = t & 31;                                  // float4 index within row
  int row = t >> 5;                                  // 0 .. 1599 (= b*N + i)
  int b = row / N;
  int i = row - b * N;                               // position in node list -> x row
  int v = nodes[row];
  float a = alpha[v];                                // alpha is (V,1)
  f32x4 wv = ((const f32x4*)W)[v * 32 + d4];
  f32x4 xv = ((const f32x4*)x)[i * 32 + d4];
  f32x4 res = (1.0f - a) * wv + a * xv;
  ((f32x4*)out)[(size_t)b * (size_t)VD4 + (size_t)(v * 32 + d4)] = res;
}

extern "C" void kernel_launch(void* const* d_in, const int* in_sizes, int n_in,
                              void* d_out, int out_size, void* d_ws, size_t ws_size,
                              hipStream_t stream) {
  const int*   nodes = (const int*)d_in[0];   // (B, N) int32
  const float* x     = (const float*)d_in[1]; // (B*N, D) f32
  const float* W     = (const float*)d_in[2]; // (V, D) f32
  const float* alpha = (const float*)d_in[3]; // (V, 1) f32
  float* out = (float*)d_out;                 // (B, V, D) f32

  GlobalGatedUpdate_copy_kernel<<<(VD4 + 1023) / 1024, 256, 0, stream>>>(
      (const f32x4*)W, (f32x4*)out);

  GlobalGatedUpdate_scatter_kernel<<<(B * N * 32) / 256, 256, 0, stream>>>(
      nodes, x, W, alpha, out);
}